// Round 8
// baseline (9894.240 us; speedup 1.0000x reference)
//
#include <hip/hip_runtime.h>

// Round 8: prefetch-before-softmax encT stream (128 full-b stream blocks),
// gh/em GEMMs overlapped on the other 128 blocks, per-group release barrier.
// Same math as R7 (absmax 0). 256 blocks x 512 threads, 3 barriers/step.

typedef unsigned short u16;
typedef unsigned int u32;
typedef __attribute__((ext_vector_type(8))) short short8;
typedef __attribute__((ext_vector_type(4))) float f32x4;
typedef __attribute__((ext_vector_type(4))) u32 u32x4;
typedef __attribute__((ext_vector_type(2))) u32 u32x2;

#define MFMA16(a, b, c) __builtin_amdgcn_mfma_f32_16x16x32_bf16((a), (b), (c), 0, 0, 0)

// ---- ws layout ----
// u16 element offsets
#define U_ENC 0u           // encT bf16 [128 b][256 t][512 c]  (32MB)
#define U_WHH 16777216u    // [1536][512]
#define U_WIH 17563648u    // [1536][512]
#define U_WAW 18350080u    // [256][768]
#define U_WOW 18546688u    // [256][512]
#define U_WCE 18677760u    // [512][256]
#define U_WXT 18808832u    // [256][256]
#define U_HB  18874368u    // h bf16 [128][512]
#define U_EB  18939904u    // e bf16 [128][256]
#define U_XB  18972672u    // x bf16 [128][512]
#define U_PB  19038208u    // p bf16 [128][256]
// f32 element offsets
#define F_LGB 9535488u     // logits f32 [128][256]
#define F_EMB 9568256u     // emissions f32 [128][256]
#define F_EPB 9601024u     // ep f32 [128][512]
#define F_GHB 9666560u     // gh f32 [128][1536]
#define F_SRB 9863168u     // CRF scores f32 [128][256]
#define F_MFB 9895936u     // [128]
#define F_NEB 9896064u     // [128]
#define F_NSB 9896192u     // [128]
#define F_BAR 9896448u     // u32: L1[771][16]x16 (197376) + REL[771] + GF[16]x16
#define REL_OFF 197376u
#define GF_OFF 198147u
#define BAR_N 198403u

__device__ __forceinline__ float bf2f(u16 u) { return __uint_as_float(((u32)u) << 16); }
__device__ __forceinline__ u16 f2bf(float f) {
  u32 u = __float_as_uint(f);
  return (u16)((u + 0x7FFFu + ((u >> 16) & 1u)) >> 16);
}
__device__ __forceinline__ u32 pk2(float a, float b) {
  return (u32)f2bf(a) | ((u32)f2bf(b) << 16);
}

// ---- coherent (sc0 sc1) load/store helpers ----
__device__ __forceinline__ float ldcg_f(const float* p) {
  float r;
  asm volatile("global_load_dword %0, %1, off sc0 sc1\n\ts_waitcnt vmcnt(0)"
               : "=v"(r) : "v"(p));
  return r;
}
__device__ __forceinline__ f32x4 ldcg_f4(const float* p) {
  f32x4 r;
  asm volatile("global_load_dwordx4 %0, %1, off sc0 sc1\n\ts_waitcnt vmcnt(0)"
               : "=v"(r) : "v"(p));
  return r;
}
__device__ __forceinline__ u32x2 ldcg_b8(const u16* p) {
  u32x2 r;
  asm volatile("global_load_dwordx2 %0, %1, off sc0 sc1\n\ts_waitcnt vmcnt(0)"
               : "=v"(r) : "v"(p));
  return r;
}
__device__ __forceinline__ void ldcg_f4x3(f32x4& a, f32x4& b, f32x4& c,
                                          const float* p0, const float* p1,
                                          const float* p2) {
  asm volatile(
      "global_load_dwordx4 %0, %3, off sc0 sc1\n\t"
      "global_load_dwordx4 %1, %4, off sc0 sc1\n\t"
      "global_load_dwordx4 %2, %5, off sc0 sc1\n\t"
      "s_waitcnt vmcnt(0)"
      : "=&v"(a), "=&v"(b), "=&v"(c)
      : "v"(p0), "v"(p1), "v"(p2));
}
__device__ __forceinline__ void ldcg8(u32x4 d[8], const u16* p) {
  asm volatile(
      "global_load_dwordx4 %0, %8, off sc0 sc1\n\t"
      "global_load_dwordx4 %1, %8, off offset:64 sc0 sc1\n\t"
      "global_load_dwordx4 %2, %8, off offset:128 sc0 sc1\n\t"
      "global_load_dwordx4 %3, %8, off offset:192 sc0 sc1\n\t"
      "global_load_dwordx4 %4, %8, off offset:256 sc0 sc1\n\t"
      "global_load_dwordx4 %5, %8, off offset:320 sc0 sc1\n\t"
      "global_load_dwordx4 %6, %8, off offset:384 sc0 sc1\n\t"
      "global_load_dwordx4 %7, %8, off offset:448 sc0 sc1\n\t"
      "s_waitcnt vmcnt(0)"
      : "=&v"(d[0]), "=&v"(d[1]), "=&v"(d[2]), "=&v"(d[3]),
        "=&v"(d[4]), "=&v"(d[5]), "=&v"(d[6]), "=&v"(d[7])
      : "v"(p));
}
__device__ __forceinline__ void ldcg16(u32x4 d[16], const u16* p) {
  asm volatile(
      "global_load_dwordx4 %0, %16, off sc0 sc1\n\t"
      "global_load_dwordx4 %1, %16, off offset:64 sc0 sc1\n\t"
      "global_load_dwordx4 %2, %16, off offset:128 sc0 sc1\n\t"
      "global_load_dwordx4 %3, %16, off offset:192 sc0 sc1\n\t"
      "global_load_dwordx4 %4, %16, off offset:256 sc0 sc1\n\t"
      "global_load_dwordx4 %5, %16, off offset:320 sc0 sc1\n\t"
      "global_load_dwordx4 %6, %16, off offset:384 sc0 sc1\n\t"
      "global_load_dwordx4 %7, %16, off offset:448 sc0 sc1\n\t"
      "global_load_dwordx4 %8, %16, off offset:512 sc0 sc1\n\t"
      "global_load_dwordx4 %9, %16, off offset:576 sc0 sc1\n\t"
      "global_load_dwordx4 %10, %16, off offset:640 sc0 sc1\n\t"
      "global_load_dwordx4 %11, %16, off offset:704 sc0 sc1\n\t"
      "global_load_dwordx4 %12, %16, off offset:768 sc0 sc1\n\t"
      "global_load_dwordx4 %13, %16, off offset:832 sc0 sc1\n\t"
      "global_load_dwordx4 %14, %16, off offset:896 sc0 sc1\n\t"
      "global_load_dwordx4 %15, %16, off offset:960 sc0 sc1\n\t"
      "s_waitcnt vmcnt(0)"
      : "=&v"(d[0]), "=&v"(d[1]), "=&v"(d[2]), "=&v"(d[3]),
        "=&v"(d[4]), "=&v"(d[5]), "=&v"(d[6]), "=&v"(d[7]),
        "=&v"(d[8]), "=&v"(d[9]), "=&v"(d[10]), "=&v"(d[11]),
        "=&v"(d[12]), "=&v"(d[13]), "=&v"(d[14]), "=&v"(d[15])
      : "v"(p));
}
__device__ __forceinline__ void stcg_f(float* p, float v) {
  asm volatile("global_store_dword %0, %1, off sc0 sc1" ::"v"(p), "v"(v) : "memory");
}
__device__ __forceinline__ void stcg_f4(float* p, f32x4 v) {
  asm volatile("global_store_dwordx4 %0, %1, off sc0 sc1" ::"v"(p), "v"(v) : "memory");
}
__device__ __forceinline__ void stcg_b8(u16* p, u32x2 v) {
  asm volatile("global_store_dwordx2 %0, %1, off sc0 sc1" ::"v"(p), "v"(v) : "memory");
}
__device__ __forceinline__ void stcg_h(u16* p, u32 v) {
  asm volatile("global_store_short %0, %1, off sc0 sc1" ::"v"(p), "v"(v) : "memory");
}

// ---- two-level barrier with per-group release (contention <= 16 per line) ----
__device__ __forceinline__ void gbar2(u32* bar, u32 gen, int blk) {
  __syncthreads();  // drains vmcnt -> this block's sc0sc1 stores visible
  if (threadIdx.x == 0) {
    const u32 grp = (u32)(blk >> 4);
    u32* l1 = bar + ((size_t)gen * 16u + grp) * 16u;
    u32* rel = bar + REL_OFF + gen;
    u32* gf = bar + GF_OFF + grp * 16u;
    const u32 old = __hip_atomic_fetch_add(l1, 1u, __ATOMIC_RELAXED,
                                           __HIP_MEMORY_SCOPE_AGENT);
    if (old == 15u)
      __hip_atomic_fetch_add(rel, 1u, __ATOMIC_RELAXED, __HIP_MEMORY_SCOPE_AGENT);
    if ((blk & 15) == 0) {  // group leader: watch global, release group
      while (__hip_atomic_load(rel, __ATOMIC_RELAXED, __HIP_MEMORY_SCOPE_AGENT) < 16u) {}
      __hip_atomic_store(gf, gen + 1u, __ATOMIC_RELAXED, __HIP_MEMORY_SCOPE_AGENT);
    } else {
      while (__hip_atomic_load(gf, __ATOMIC_RELAXED, __HIP_MEMORY_SCOPE_AGENT) < gen + 1u) {}
    }
  }
  __syncthreads();
}

// ---------------- weight convert to bf16 ----------------
__global__ void __launch_bounds__(256) kPrep(const float* __restrict__ wih,
                                             const float* __restrict__ whh,
                                             const float* __restrict__ aW,
                                             const float* __restrict__ oW,
                                             const float* __restrict__ cW,
                                             const float* __restrict__ ct,
                                             float* __restrict__ ws) {
  u16* W = (u16*)ws;
  const u32 i = blockIdx.x * 256 + threadIdx.x;
  if (i < 786432u) {
    W[U_WHH + i] = f2bf(whh[i]);
  } else if (i < 1572864u) {
    const u32 j = i - 786432u;
    W[U_WIH + j] = f2bf(wih[j]);
  } else if (i < 1769472u) {
    const u32 j = i - 1572864u;
    W[U_WAW + j] = f2bf(aW[j]);
  } else if (i < 1900544u) {
    const u32 j = i - 1769472u;
    W[U_WOW + j] = f2bf(oW[j]);
  } else if (i < 2031616u) {
    const u32 j = i - 1900544u;
    W[U_WCE + j] = f2bf(cW[(size_t)(j >> 8) * 1280 + (j & 255u)]);
  } else {
    const u32 j = i - 2031616u;
    const u32 kn = j >> 8, k = j & 255u;
    W[U_WXT + j] = f2bf(__expf(ct[k * 256u + kn]));
  }
}

// ---------------- init ----------------
__global__ void __launch_bounds__(256) kInit(const int* __restrict__ dec,
                                             const int* __restrict__ tags,
                                             const float* __restrict__ emb,
                                             const float* __restrict__ cs,
                                             const float* __restrict__ ce,
                                             const float* __restrict__ ct,
                                             float* __restrict__ ws) {
  const u32 idx = blockIdx.x * 256 + threadIdx.x;  // 65536
  u16* ENC = (u16*)ws;
  u16* HB = ENC + U_HB;
  u16* EB = ENC + U_EB;
  if (idx < 32768u) {
    ((u32*)HB)[idx] = 0u;
    const int b = idx >> 8, j = idx & 255;
    EB[idx] = f2bf(emb[(size_t)dec[b] * 256 + j]);
  }
  if (idx < 128u) {
    int prev = tags[idx];
    float a = cs[prev];
    for (int t = 1; t < 256; ++t) {
      const int cur = tags[t * 128 + idx];
      a += ct[prev * 256 + cur];
      prev = cur;
    }
    ws[F_NSB + idx] = a + ce[prev];
    ws[F_NEB + idx] = 0.f;
  }
  u32* bar = (u32*)(ws + F_BAR);
  if (idx < 49601u) {
#pragma unroll
    for (int j = 0; j < 4; ++j) {
      const u32 k = idx * 4u + (u32)j;
      if (k < BAR_N) bar[k] = 0u;
    }
  }
}

// ---------------- encT[b][t][c] = sum_j enc[t,b,j] * comb_W[c, 256+j] ----------------
__global__ void __launch_bounds__(256) kEncW(const float* __restrict__ enc,
                                             const float* __restrict__ cW,
                                             u16* __restrict__ encT) {
  __shared__ float wL[64 * 64];
  const int t = blockIdx.x >> 3, cblk = blockIdx.x & 7;
  const int tid = threadIdx.x;
  const int bg = tid & 31;
  const int cg = tid >> 5;
  float acc[4][8];
#pragma unroll
  for (int i = 0; i < 4; ++i)
#pragma unroll
    for (int c = 0; c < 8; ++c) acc[i][c] = 0.f;
  const float* encB = enc + (size_t)t * (128 * 1024);
  for (int jt = 0; jt < 16; ++jt) {
    const int j0 = jt * 64;
    __syncthreads();
    for (int i = tid; i < 4096; i += 256) {
      const int cc = i >> 6, jj = i & 63;
      wL[cc * 64 + jj] = cW[(size_t)(cblk * 64 + cc) * 1280 + 256 + j0 + jj];
    }
    __syncthreads();
    for (int jj = 0; jj < 64; ++jj) {
      const float e0 = encB[(bg * 4 + 0) * 1024 + j0 + jj];
      const float e1 = encB[(bg * 4 + 1) * 1024 + j0 + jj];
      const float e2 = encB[(bg * 4 + 2) * 1024 + j0 + jj];
      const float e3 = encB[(bg * 4 + 3) * 1024 + j0 + jj];
#pragma unroll
      for (int c = 0; c < 8; ++c) {
        const float wv = wL[(cg * 8 + c) * 64 + jj];
        acc[0][c] = fmaf(e0, wv, acc[0][c]);
        acc[1][c] = fmaf(e1, wv, acc[1][c]);
        acc[2][c] = fmaf(e2, wv, acc[2][c]);
        acc[3][c] = fmaf(e3, wv, acc[3][c]);
      }
    }
  }
#pragma unroll
  for (int i = 0; i < 4; ++i)
    for (int c = 0; c < 8; ++c) {
      const int b = bg * 4 + i, cc = cblk * 64 + cg * 8 + c;
      encT[(size_t)b * 131072u + (size_t)t * 512u + cc] = f2bf(acc[i][c]);
    }
}

struct P9 {
  const int* dec; const int* tags; const float* emb;
  const float* ab; const float* cb; const float* bih; const float* bhh;
  const float* ob; const float* cs;
  float* ws;
};

// ---------------- main cooperative kernel ----------------
__global__ void __launch_bounds__(512, 2) maink(P9 p) {
  float* const ws = p.ws;
  u16* const ENC = (u16*)ws;
  const u16* const WHH16 = ENC + U_WHH;
  const u16* const WIH16 = ENC + U_WIH;
  const u16* const WAW16 = ENC + U_WAW;
  const u16* const WOW16 = ENC + U_WOW;
  const u16* const WCE16 = ENC + U_WCE;
  const u16* const WXT16 = ENC + U_WXT;
  u16* const HB = ENC + U_HB;
  u16* const EB = ENC + U_EB;
  u16* const XB = ENC + U_XB;
  u16* const PBu = ENC + U_PB;
  float* const LGB = ws + F_LGB;
  float* const EMB = ws + F_EMB;
  float* const EPB = ws + F_EPB;
  float* const GHB = ws + F_GHB;
  float* const SRB = ws + F_SRB;
  float* const MFB = ws + F_MFB;
  float* const NEB = ws + F_NEB;
  u32* const bar = (u32*)(ws + F_BAR);

  __shared__ float PL[8 * 576];   // stream partials, pad-9
  __shared__ float pr3[3][256];

  const int tid = threadIdx.x;
  const int w = tid >> 6, lane = tid & 63;
  const int bq = lane & 15, kg = lane >> 4;
  const int blk = blockIdx.x;
  u32 gen = 0;

  for (int s = 0; s <= 256; ++s) {
    // ================= P1: logits + ep + CRF-A =================
    if (blk < 128) {
      if (w == 0) {
        if (s < 256) {  // attn logits, K=768
          const int r0 = (blk >> 3) * 16, b0 = (blk & 7) * 16;
          f32x4 acc;
          const float4 bs = *(const float4*)(p.ab + r0 + kg * 4);
          acc[0] = bs.x; acc[1] = bs.y; acc[2] = bs.z; acc[3] = bs.w;
          u32x4 Ef[8], Hf[16];
          ldcg8(Ef, EB + (size_t)(b0 + bq) * 256 + kg * 8);
          ldcg16(Hf, HB + (size_t)(b0 + bq) * 512 + kg * 8);
          const u16* Ar = WAW16 + (size_t)(r0 + bq) * 768 + kg * 8;
#pragma unroll
          for (int kt = 0; kt < 8; ++kt)
            acc = MFMA16(*(const short8*)(Ar + kt * 32),
                         __builtin_bit_cast(short8, Ef[kt]), acc);
#pragma unroll
          for (int kt = 0; kt < 16; ++kt)
            acc = MFMA16(*(const short8*)(Ar + 256 + kt * 32),
                         __builtin_bit_cast(short8, Hf[kt]), acc);
          stcg_f4(LGB + (size_t)(b0 + bq) * 256 + r0 + kg * 4, acc);
        }
      } else if (w == 5) {
        if (s >= 2) {  // CRF-A
          const int b = blk;
          const f32x4 sv = ldcg_f4(SRB + (size_t)b * 256 + lane * 4);
          float mx = fmaxf(fmaxf(sv[0], sv[1]), fmaxf(sv[2], sv[3]));
#pragma unroll
          for (int o = 32; o; o >>= 1) mx = fmaxf(mx, __shfl_xor(mx, o));
          u32x2 pv;
          pv[0] = pk2(__expf(sv[0] - mx), __expf(sv[1] - mx));
          pv[1] = pk2(__expf(sv[2] - mx), __expf(sv[3] - mx));
          stcg_b8(PBu + (size_t)b * 256 + lane * 4, pv);
          if (lane == 0) stcg_f(MFB + b, mx);
        }
      }
    } else {
      if (w < 2 && s < 256) {  // ep tiles: 2 per block
        const int id = (blk - 128) * 2 + w;
        const int r0 = (id >> 3) * 16, b0 = (id & 7) * 16;
        f32x4 acc;
        const float4 bs = *(const float4*)(p.cb + r0 + kg * 4);
        acc[0] = bs.x; acc[1] = bs.y; acc[2] = bs.z; acc[3] = bs.w;
        u32x4 Ef[8];
        ldcg8(Ef, EB + (size_t)(b0 + bq) * 256 + kg * 8);
        const u16* Ar = WCE16 + (size_t)(r0 + bq) * 256 + kg * 8;
#pragma unroll
        for (int kt = 0; kt < 8; ++kt)
          acc = MFMA16(*(const short8*)(Ar + kt * 32),
                       __builtin_bit_cast(short8, Ef[kt]), acc);
        stcg_f4(EPB + (size_t)(b0 + bq) * 512 + r0 + kg * 4, acc);
      }
    }
    gbar2(bar, gen++, blk);

    // ================= P2: stream (blk<128) || gh+em (blk>=128) =================
    if (blk < 128) {
      if (s < 256) {
        const int b = blk;
        // 1) logits row (waits vmcnt(0) internally)
        const f32x4 lg = ldcg_f4(LGB + (size_t)b * 256 + lane * 4);
        // 2) issue the full encT slice for this warp's 32 t's (NT, in-flight)
        const u16* sbase = ENC + (size_t)b * 131072u + (size_t)(w * 32) * 512u + lane * 8;
        u32x4 dv[32];
#pragma unroll
        for (int j = 0; j < 32; ++j)
          dv[j] = __builtin_nontemporal_load(
              reinterpret_cast<const u32x4*>(sbase + (size_t)j * 512));
        // 3) per-wave softmax over 256 logits (register-only, no __syncthreads)
        float m = fmaxf(fmaxf(lg[0], lg[1]), fmaxf(lg[2], lg[3]));
#pragma unroll
        for (int o = 32; o; o >>= 1) m = fmaxf(m, __shfl_xor(m, o));
        f32x4 pr;
        float sm = 0.f;
#pragma unroll
        for (int i = 0; i < 4; ++i) { pr[i] = __expf(lg[i] - m); sm += pr[i]; }
#pragma unroll
        for (int o = 32; o; o >>= 1) sm += __shfl_xor(sm, o);
        const float inv = 1.f / sm;
        // 4) extract this warp's 32 pr values
        float prr[32];
#pragma unroll
        for (int j = 0; j < 32; ++j)
          prr[j] = __shfl(pr[j & 3], w * 8 + (j >> 2), 64);
        // 5) FMA from prefetched registers
        float acc[8];
#pragma unroll
        for (int i = 0; i < 8; ++i) acc[i] = 0.f;
#pragma unroll
        for (int j = 0; j < 32; ++j) {
          const u32x4 v = dv[j];
#pragma unroll
          for (int q = 0; q < 4; ++q) {
            acc[2 * q] = fmaf(prr[j], bf2f((u16)(v[q] & 0xffffu)), acc[2 * q]);
            acc[2 * q + 1] = fmaf(prr[j], bf2f((u16)(v[q] >> 16)), acc[2 * q + 1]);
          }
        }
        // 6) cross-warp reduce + x
#pragma unroll
        for (int i = 0; i < 8; ++i) PL[w * 576 + lane * 9 + i] = acc[i];
        __syncthreads();
        const int c = tid;
        float s8 = 0.f;
#pragma unroll
        for (int ww = 0; ww < 8; ++ww) s8 += PL[ww * 576 + c + (c >> 3)];
        const float xv = fmaxf(ldcg_f(EPB + (size_t)b * 512 + c) + s8 * inv, 0.f);
        stcg_h(XB + (size_t)b * 512 + c, (u32)f2bf(xv));
      }
    } else {
      const int id = (blk - 128) * 8 + w;
      if (id < 768) {
        if (s < 256) {  // gh tile
          const int r0 = (id >> 3) * 16, b0 = (id & 7) * 16;
          f32x4 acc;
          const float4 bs = *(const float4*)(p.bhh + r0 + kg * 4);
          acc[0] = bs.x; acc[1] = bs.y; acc[2] = bs.z; acc[3] = bs.w;
          u32x4 Bf[16];
          ldcg16(Bf, HB + (size_t)(b0 + bq) * 512 + kg * 8);
          const u16* Ar = WHH16 + (size_t)(r0 + bq) * 512 + kg * 8;
#pragma unroll
          for (int kt = 0; kt < 16; ++kt)
            acc = MFMA16(*(const short8*)(Ar + kt * 32),
                         __builtin_bit_cast(short8, Bf[kt]), acc);
          stcg_f4(GHB + (size_t)(b0 + bq) * 1536 + r0 + kg * 4, acc);
        }
      } else if (id < 896) {
        if (s >= 1) {  // em_{s-1} tile from current h
          const int t2 = id - 768;
          const int r0 = (t2 >> 3) * 16, b0 = (t2 & 7) * 16;
          f32x4 acc;
          const float4 bs = *(const float4*)(p.ob + r0 + kg * 4);
          acc[0] = bs.x; acc[1] = bs.y; acc[2] = bs.z; acc[3] = bs.w;
          u32x4 Hf[16];
          ldcg16(Hf, HB + (size_t)(b0 + bq) * 512 + kg * 8);
          const u16* Ar = WOW16 + (size_t)(r0 + bq) * 512 + kg * 8;
#pragma unroll
          for (int kt = 0; kt < 16; ++kt)
            acc = MFMA16(*(const short8*)(Ar + kt * 32),
                         __builtin_bit_cast(short8, Hf[kt]), acc);
          stcg_f4(EMB + (size_t)(b0 + bq) * 256 + r0 + kg * 4, acc);
        }
      }
    }
    gbar2(bar, gen++, blk);

    // ================= P3: gi + gates + h ; CRF-B ; e-stage ; NEB =================
    f32x4 R, Z, N;
    const bool giact = (s < 256) && (w == 0 || w == 2);
    if (giact) {
      const int r0 = (blk >> 3) * 16, b0 = (blk & 7) * 16;
      const int kh = w >> 1;
      if (kh == 0) {
        const float4 b1 = *(const float4*)(p.bih + r0 + kg * 4);
        const float4 b2 = *(const float4*)(p.bih + 512 + r0 + kg * 4);
        const float4 b3 = *(const float4*)(p.bih + 1024 + r0 + kg * 4);
        R[0] = b1.x; R[1] = b1.y; R[2] = b1.z; R[3] = b1.w;
        Z[0] = b2.x; Z[1] = b2.y; Z[2] = b2.z; Z[3] = b2.w;
        N[0] = b3.x; N[1] = b3.y; N[2] = b3.z; N[3] = b3.w;
      } else {
        R = (f32x4){0.f, 0.f, 0.f, 0.f}; Z = R; N = R;
      }
      u32x4 Xf[8];
      ldcg8(Xf, XB + (size_t)(b0 + bq) * 512 + kh * 256 + kg * 8);
      const u16* ArR = WIH16 + (size_t)(r0 + bq) * 512 + kh * 256 + kg * 8;
      const u16* ArZ = ArR + (size_t)512 * 512;
      const u16* ArN = ArR + (size_t)1024 * 512;
#pragma unroll
      for (int kt = 0; kt < 8; ++kt) {
        const short8 bb = __builtin_bit_cast(short8, Xf[kt]);
        R = MFMA16(*(const short8*)(ArR + kt * 32), bb, R);
        Z = MFMA16(*(const short8*)(ArZ + kt * 32), bb, Z);
        N = MFMA16(*(const short8*)(ArN + kt * 32), bb, N);
      }
      if (w == 2) {
#pragma unroll
        for (int r = 0; r < 4; ++r) {
          pr3[0][(kg * 4 + r) * 16 + bq] = R[r];
          pr3[1][(kg * 4 + r) * 16 + bq] = Z[r];
          pr3[2][(kg * 4 + r) * 16 + bq] = N[r];
        }
      }
    }
    __syncthreads();
    if (s < 256 && w == 0) {  // combine + gates + h_new
      const int r0 = (blk >> 3) * 16, b0 = (blk & 7) * 16;
      const int b = b0 + bq;
      f32x4 gr4, gz4, gn4;
      ldcg_f4x3(gr4, gz4, gn4,
                GHB + (size_t)b * 1536 + r0 + kg * 4,
                GHB + (size_t)b * 1536 + 512 + r0 + kg * 4,
                GHB + (size_t)b * 1536 + 1024 + r0 + kg * 4);
      const u32x2 h4 = ldcg_b8(HB + (size_t)b * 512 + r0 + kg * 4);
      const float hold[4] = {bf2f((u16)(h4[0] & 0xffffu)), bf2f((u16)(h4[0] >> 16)),
                             bf2f((u16)(h4[1] & 0xffffu)), bf2f((u16)(h4[1] >> 16))};
      float hn[4];
#pragma unroll
      for (int r = 0; r < 4; ++r) {
        const float Rv = R[r] + pr3[0][(kg * 4 + r) * 16 + bq];
        const float Zv = Z[r] + pr3[1][(kg * 4 + r) * 16 + bq];
        const float Nv = N[r] + pr3[2][(kg * 4 + r) * 16 + bq];
        const float rr = 1.f / (1.f + __expf(-(Rv + gr4[r])));
        const float zz = 1.f / (1.f + __expf(-(Zv + gz4[r])));
        const float nn = tanhf(Nv + rr * gn4[r]);
        hn[r] = (1.f - zz) * nn + zz * hold[r];
      }
      u32x2 ho;
      ho[0] = pk2(hn[0], hn[1]);
      ho[1] = pk2(hn[2], hn[3]);
      stcg_b8(HB + (size_t)b * 512 + r0 + kg * 4, ho);
    }
    if (w == 1) {
      if (blk < 128) {
        if (s >= 1) {  // CRF-B
          const int kn0 = (blk >> 3) * 16, b0 = (blk & 7) * 16;
          const int b = b0 + bq;
          if (s == 1) {
            const f32x4 e4 = ldcg_f4(EMB + (size_t)b * 256 + kn0 + kg * 4);
            const float4 c4 = *(const float4*)(p.cs + kn0 + kg * 4);
            f32x4 o;
            o[0] = c4.x + e4[0]; o[1] = c4.y + e4[1];
            o[2] = c4.z + e4[2]; o[3] = c4.w + e4[3];
            stcg_f4(SRB + (size_t)b * 256 + kn0 + kg * 4, o);
          } else {
            f32x4 acc = (f32x4){0.f, 0.f, 0.f, 0.f};
            u32x4 Pf[8];
            ldcg8(Pf, PBu + (size_t)(b0 + bq) * 256 + kg * 8);
            const u16* Ar = WXT16 + (size_t)(kn0 + bq) * 256 + kg * 8;
#pragma unroll
            for (int kt = 0; kt < 8; ++kt)
              acc = MFMA16(*(const short8*)(Ar + kt * 32),
                           __builtin_bit_cast(short8, Pf[kt]), acc);
            const float mf = ldcg_f(MFB + b);
            const f32x4 e4 = ldcg_f4(EMB + (size_t)b * 256 + kn0 + kg * 4);
            f32x4 o;
            o[0] = mf + __logf(acc[0]) + e4[0];
            o[1] = mf + __logf(acc[1]) + e4[1];
            o[2] = mf + __logf(acc[2]) + e4[2];
            o[3] = mf + __logf(acc[3]) + e4[3];
            stcg_f4(SRB + (size_t)b * 256 + kn0 + kg * 4, o);
          }
        }
      } else {
        if (s < 255) {  // stage e_{s+1}
          const int b = blk - 128;
          const int tok = p.tags[s * 128 + b];
          const float4 ev = *(const float4*)(p.emb + (size_t)tok * 256 + lane * 4);
          u32x2 ee;
          ee[0] = pk2(ev.x, ev.y);
          ee[1] = pk2(ev.z, ev.w);
          stcg_b8(EB + (size_t)b * 256 + lane * 4, ee);
        }
      }
    }
    if (w == 3 && blk < 128 && s >= 1 && lane == 0) {  // numerator gather
      const int tg = p.tags[(s - 1) * 128 + blk];
      const float em = ldcg_f(EMB + (size_t)blk * 256 + tg);
      const float ne = ldcg_f(NEB + blk);
      stcg_f(NEB + blk, ne + em);
    }
    gbar2(bar, gen++, blk);
  }
}

// ---------------- final: denominator + mean ----------------
__global__ void __launch_bounds__(128) kFinal(const float* __restrict__ ws,
                                              const float* __restrict__ ce,
                                              float* __restrict__ out) {
  __shared__ float acc[128];
  const int tid = threadIdx.x;  // 128
  const float* SRB = ws + F_SRB;
  float mx = -3.0e38f;
#pragma unroll 8
  for (int k = 0; k < 256; ++k) mx = fmaxf(mx, SRB[(size_t)tid * 256 + k] + ce[k]);
  float sm = 0.f;
#pragma unroll 8
  for (int k = 0; k < 256; ++k) sm += __expf(SRB[(size_t)tid * 256 + k] + ce[k] - mx);
  acc[tid] = ws[F_NSB + tid] + ws[F_NEB + tid] - (mx + __logf(sm));
  __syncthreads();
  if (tid < 64) {
    float v = acc[tid] + acc[tid + 64];
#pragma unroll
    for (int o = 32; o; o >>= 1) v += __shfl_xor(v, o);
    if (tid == 0) out[0] = v * (1.f / 128.f);
  }
}

extern "C" void kernel_launch(void* const* d_in, const int* in_sizes, int n_in,
                              void* d_out, int out_size, void* d_ws, size_t ws_size,
                              hipStream_t stream) {
  (void)in_sizes; (void)n_in; (void)out_size; (void)ws_size;
  const int* dec = (const int*)d_in[0];
  const int* tags = (const int*)d_in[1];
  const float* enc = (const float*)d_in[2];
  const float* emb = (const float*)d_in[3];
  const float* aW = (const float*)d_in[4];
  const float* ab = (const float*)d_in[5];
  const float* cW = (const float*)d_in[6];
  const float* cb = (const float*)d_in[7];
  const float* wih = (const float*)d_in[8];
  const float* whh = (const float*)d_in[9];
  const float* bih = (const float*)d_in[10];
  const float* bhh = (const float*)d_in[11];
  const float* oW = (const float*)d_in[12];
  const float* ob = (const float*)d_in[13];
  const float* cs = (const float*)d_in[14];
  const float* ce = (const float*)d_in[15];
  const float* ct = (const float*)d_in[16];
  float* ws = (float*)d_ws;
  float* out = (float*)d_out;

  kPrep<<<dim3(8192), dim3(256), 0, stream>>>(wih, whh, aW, oW, cW, ct, ws);
  kInit<<<dim3(256), dim3(256), 0, stream>>>(dec, tags, emb, cs, ce, ct, ws);
  kEncW<<<dim3(2048), dim3(256), 0, stream>>>(enc, cW, (u16*)d_ws);

  P9 p;
  p.dec = dec; p.tags = tags; p.emb = emb;
  p.ab = ab; p.cb = cb; p.bih = bih; p.bhh = bhh;
  p.ob = ob; p.cs = cs; p.ws = ws;
  void* args[] = { &p };
  hipLaunchCooperativeKernel((void*)maink, dim3(256), dim3(512), args, 0, stream);

  kFinal<<<dim3(1), dim3(128), 0, stream>>>(ws, ce, out);
}